// Round 2
// baseline (372971.045 us; speedup 1.0000x reference)
//
#include <hip/hip_runtime.h>
#include <cstdint>
#include <cstddef>
#include <cmath>

// ---------------------------------------------------------------------------
// LiveSAL fp32 implementation, round 2: slice-granular schedule to shrink
// workspace from ~795 MB to ~167 MB (suspected R1 crash = d_ws overflow).
// d_out doubles as the hi/comb arena. All math identical to R1.
// ---------------------------------------------------------------------------

#define Sn 5
#define Bn 128
#define Cn 256
#define Nn 121          // 11*11
#define HEADSn 8
#define NITERn 2
#define EPSf 1e-5f
#define SCALEf 0.0625f  // 256^-0.5
#define CHWn (Cn*Nn)    // 30976

static const size_t SLICEsz = (size_t)Bn*CHWn;       // 3,964,928 floats
static const size_t FULLsz  = (size_t)Sn*SLICEsz;    // 19,824,640 floats
static const size_t SLA     = SLICEsz + 1024;        // padded slice arena

// ---------------------------------------------------------------------------
// LayerNorm over (C,H,W) per sample (one block per sample).
// out = alpha * maybe_relu(LN(x)*g+b) + addend
// ---------------------------------------------------------------------------
__global__ __launch_bounds__(256) void ln_kernel(
    const float* __restrict__ x, const float* __restrict__ g, const float* __restrict__ bb,
    float* __restrict__ out, const float* __restrict__ alpha,
    const float* __restrict__ addend, int relu)
{
  const size_t base = (size_t)blockIdx.x * CHWn;
  const float* xs = x + base;
  float sum = 0.f, ss = 0.f;
  for (int i = threadIdx.x; i < CHWn; i += 256){
    float v = xs[i]; sum += v; ss += v*v;
  }
  #pragma unroll
  for (int o = 32; o > 0; o >>= 1){ sum += __shfl_down(sum, o, 64); ss += __shfl_down(ss, o, 64); }
  __shared__ float r1[4], r2[4];
  const int wid = threadIdx.x >> 6;
  if ((threadIdx.x & 63) == 0){ r1[wid] = sum; r2[wid] = ss; }
  __syncthreads();
  sum = r1[0]+r1[1]+r1[2]+r1[3];
  ss  = r2[0]+r2[1]+r2[2]+r2[3];
  const float mean = sum * (1.f/CHWn);
  const float var  = ss * (1.f/CHWn) - mean*mean;
  const float inv  = rsqrtf(var + EPSf);
  const float a = alpha ? *alpha : 1.f;
  float* os = out + base;
  const float* ad = addend ? addend + base : nullptr;
  for (int i = threadIdx.x; i < CHWn; i += 256){
    float v = (xs[i] - mean) * inv * g[i] + bb[i];
    if (relu) v = fmaxf(v, 0.f);
    v *= a;
    if (ad) v += ad[i];
    os[i] = v;
  }
}

// ---------------------------------------------------------------------------
// Direct 3x3 conv, pad=1, 11x11. Input = virtual concat of inA (cinA ch) and
// inB. 128 thr (1/pixel), 64 couts/block. grid = (Nb, Cout/64).
// Weight index is wave-uniform -> scalar loads feeding v_fma.
// ---------------------------------------------------------------------------
__global__ __launch_bounds__(128) void conv3x3_kernel(
    const float* __restrict__ inA, const float* __restrict__ inB,
    int cinA, int Cin, int Cout,
    const float* __restrict__ w, const float* __restrict__ bias,
    float* __restrict__ out)
{
  __shared__ float plbuf[2*122];
  const int n = blockIdx.x;
  const int co0 = blockIdx.y * 64;
  const int t = threadIdx.x;
  const bool act = t < Nn;
  const int y = t / 11, x = t % 11;
  int off[9];
  if (act){
    #pragma unroll
    for (int dy=0; dy<3; dy++)
      #pragma unroll
      for (int dx=0; dx<3; dx++){
        int yy = y+dy-1, xx = x+dx-1;
        bool ok = (yy>=0)&&(yy<11)&&(xx>=0)&&(xx<11);
        off[dy*3+dx] = ok ? yy*11+xx : 121;  // 121 = zero sentinel
      }
  }
  if (t < 2) plbuf[t*122 + 121] = 0.f;
  float acc[64];
  #pragma unroll
  for (int c=0;c<64;c++) acc[c] = bias[co0+c];
  const float* baseA = inA + (size_t)n*cinA*Nn;
  const float* baseB = inB ? (inB + (size_t)n*(size_t)(Cin-cinA)*Nn) : nullptr;
  for (int ci0 = 0; ci0 < Cin; ci0 += 2){
    const int npl = (Cin - ci0) >= 2 ? 2 : 1;
    __syncthreads();
    for (int l = t; l < Nn*npl; l += 128){
      int cl = (l >= Nn) ? 1 : 0; int p = l - cl*Nn;
      int ci = ci0 + cl;
      plbuf[cl*122+p] = (ci < cinA) ? baseA[(size_t)ci*Nn+p]
                                    : baseB[(size_t)(ci-cinA)*Nn+p];
    }
    __syncthreads();
    if (act){
      for (int cl=0; cl<npl; cl++){
        const int ci = ci0+cl;
        float nb[9];
        #pragma unroll
        for (int j=0;j<9;j++) nb[j] = plbuf[cl*122 + off[j]];
        const float* wr = w + ((size_t)co0*Cin + ci)*9;
        #pragma unroll
        for (int c=0;c<64;c++){
          #pragma unroll
          for (int j=0;j<9;j++) acc[c] = fmaf(nb[j], wr[(size_t)c*Cin*9 + j], acc[c]);
        }
      }
    }
  }
  if (act){
    float* ob = out + ((size_t)n*Cout + co0)*Nn + t;
    #pragma unroll
    for (int c=0;c<64;c++) ob[(size_t)c*Nn] = acc[c];
  }
}

// ---------------------------------------------------------------------------
// m-conv for one (i,j) pair: input = concat[h_j (256ch), tenc0, tenc1, rpe_row]
// = 259 ch. grid = (Bn, 4).
// ---------------------------------------------------------------------------
__global__ __launch_bounds__(128) void conv3x3_m_kernel(
    const float* __restrict__ hj, const float* __restrict__ rp,
    float tc0, float tc1,
    const float* __restrict__ w, const float* __restrict__ bias,
    float* __restrict__ out)
{
  __shared__ float plbuf[2*122];
  const int n = blockIdx.x;
  const int co0 = blockIdx.y * 64;
  const int t = threadIdx.x;
  const bool act = t < Nn;
  const int y = t / 11, x = t % 11;
  int off[9];
  if (act){
    #pragma unroll
    for (int dy=0; dy<3; dy++)
      #pragma unroll
      for (int dx=0; dx<3; dx++){
        int yy = y+dy-1, xx = x+dx-1;
        bool ok = (yy>=0)&&(yy<11)&&(xx>=0)&&(xx<11);
        off[dy*3+dx] = ok ? yy*11+xx : 121;
      }
  }
  if (t < 2) plbuf[t*122 + 121] = 0.f;
  float acc[64];
  #pragma unroll
  for (int c=0;c<64;c++) acc[c] = bias[co0+c];
  const float* baseH = hj + (size_t)n*Cn*Nn;
  const int Cin = 259;
  for (int ci0 = 0; ci0 < Cin; ci0 += 2){
    const int npl = (Cin - ci0) >= 2 ? 2 : 1;
    __syncthreads();
    for (int l = t; l < Nn*npl; l += 128){
      int cl = (l >= Nn) ? 1 : 0; int p = l - cl*Nn;
      int ci = ci0 + cl;
      float val;
      if (ci < 256)       val = baseH[(size_t)ci*Nn + p];
      else if (ci == 256) val = tc0;
      else if (ci == 257) val = tc1;
      else                val = rp[p];
      plbuf[cl*122+p] = val;
    }
    __syncthreads();
    if (act){
      for (int cl=0; cl<npl; cl++){
        const int ci = ci0+cl;
        float nb[9];
        #pragma unroll
        for (int j=0;j<9;j++) nb[j] = plbuf[cl*122 + off[j]];
        const float* wr = w + ((size_t)co0*Cin + ci)*9;
        #pragma unroll
        for (int c=0;c<64;c++){
          #pragma unroll
          for (int j=0;j<9;j++) acc[c] = fmaf(nb[j], wr[(size_t)c*Cin*9 + j], acc[c]);
        }
      }
    }
  }
  if (act){
    float* ob = out + ((size_t)n*Cn + co0)*Nn + t;
    #pragma unroll
    for (int c=0;c<64;c++) ob[(size_t)c*Nn] = acc[c];
  }
}

// ---------------------------------------------------------------------------
// Fused attention per (sample, head); q/k/v share sample index (slice-local).
// Scores 8x8 register-blocked into S^T in LDS (121x132 = 63.9 KB), in-LDS
// softmax (thread-per-query column scan), register-blocked AV.
// ---------------------------------------------------------------------------
template<int HDt, int CPT, int NPASS>
__global__ __launch_bounds__(256) void attn_kernel(
    const float* __restrict__ q, const float* __restrict__ k, const float* __restrict__ v,
    float* __restrict__ o)
{
  __shared__ float T[Nn*132];
  const int nh_ = Cn / HDt;
  const int samp = blockIdx.x / nh_;
  const int hh = blockIdx.x % nh_;
  const size_t koff = ((size_t)samp*Cn + hh*HDt)*Nn;
  const int t = threadIdx.x;
  {
    const int tn = t >> 4, tm = t & 15;
    const int n0 = tn*8, m0 = tm*8;
    float acc[8][8];
    #pragma unroll
    for (int a2=0;a2<8;a2++)
      #pragma unroll
      for (int b2=0;b2<8;b2++) acc[a2][b2] = 0.f;
    const float* qp = q + koff + n0;
    const float* kp = k + koff + m0;
    #pragma unroll 2
    for (int d=0; d<HDt; ++d){
      float qv[8], kv[8];
      #pragma unroll
      for (int j2=0;j2<8;j2++){ qv[j2] = qp[d*Nn + j2]; kv[j2] = kp[d*Nn + j2]; }
      #pragma unroll
      for (int a2=0;a2<8;a2++)
        #pragma unroll
        for (int b2=0;b2<8;b2++) acc[a2][b2] = fmaf(qv[a2], kv[b2], acc[a2][b2]);
    }
    #pragma unroll
    for (int b2=0;b2<8;b2++){
      const int m = m0 + b2;
      if (m < Nn){
        #pragma unroll
        for (int a2=0;a2<8;a2++) T[m*132 + n0 + a2] = acc[a2][b2] * SCALEf;
      }
    }
  }
  __syncthreads();
  if (t < Nn){
    float mx = -1e30f;
    for (int m2=0;m2<Nn;m2++) mx = fmaxf(mx, T[m2*132+t]);
    float sum = 0.f;
    for (int m2=0;m2<Nn;m2++){ float e = __expf(T[m2*132+t]-mx); sum += e; T[m2*132+t] = e; }
    const float invs = 1.f/sum;
    for (int m2=0;m2<Nn;m2++) T[m2*132+t] *= invs;
  }
  __syncthreads();
  {
    const int ng_ = t & 15, cg = t >> 4;
    const int an0 = ng_*8;
    for (int pass=0; pass<NPASS; ++pass){
      const int c0 = pass*64 + cg*CPT;
      float av[CPT][8];
      #pragma unroll
      for (int ci2=0;ci2<CPT;ci2++)
        #pragma unroll
        for (int j2=0;j2<8;j2++) av[ci2][j2] = 0.f;
      for (int m2=0;m2<Nn;m2++){
        float tv[8];
        #pragma unroll
        for (int j2=0;j2<8;j2++) tv[j2] = T[m2*132 + an0 + j2];
        #pragma unroll
        for (int ci2=0;ci2<CPT;ci2++){
          const float vv = v[koff + (size_t)(c0+ci2)*Nn + m2];
          #pragma unroll
          for (int j2=0;j2<8;j2++) av[ci2][j2] = fmaf(vv, tv[j2], av[ci2][j2]);
        }
      }
      #pragma unroll
      for (int ci2=0;ci2<CPT;ci2++){
        float* op = o + koff + (size_t)(c0+ci2)*Nn + an0;
        #pragma unroll
        for (int j2=0;j2<8;j2++) if (an0+j2 < Nn) op[j2] = av[ci2][j2];
      }
    }
  }
}

// Spatial mean per (local sample, channel). grid=(Bn,32).
__global__ __launch_bounds__(128) void mean_kernel(const float* __restrict__ x, float* __restrict__ out)
{
  const int s = blockIdx.x; const int c0 = blockIdx.y*8;
  __shared__ float r[2];
  for (int cc=0; cc<8; ++cc){
    const int c = c0+cc;
    float v = 0.f;
    if (threadIdx.x < Nn) v = x[((size_t)s*Cn + c)*Nn + threadIdx.x];
    #pragma unroll
    for (int o=32;o>0;o>>=1) v += __shfl_down(v, o, 64);
    if ((threadIdx.x & 63) == 0) r[threadIdx.x>>6] = v;
    __syncthreads();
    if (threadIdx.x == 0) out[(size_t)s*Cn + c] = (r[0]+r[1]) * (1.f/Nn);
    __syncthreads();
  }
}

// gate[b,c] = sigmoid( gw[c,:] . [meanX(b); meanM(b)] + gb[c] )  (exact: mean
// commutes with the 1x1 conv). grid=Bn, block=256.
__global__ __launch_bounds__(256) void gate_kernel(
    const float* __restrict__ meanX, const float* __restrict__ meanM,
    const float* __restrict__ gw, const float* __restrict__ gb,
    float* __restrict__ gate)
{
  const int b = blockIdx.x;
  __shared__ float mv[512];
  mv[threadIdx.x]     = meanX[(size_t)b*Cn + threadIdx.x];
  mv[256+threadIdx.x] = meanM[(size_t)b*Cn + threadIdx.x];
  __syncthreads();
  const float* gr = gw + (size_t)threadIdx.x*512;
  float acc = gb[threadIdx.x];
  for (int k2=0;k2<512;k2++) acc = fmaf(gr[k2], mv[k2], acc);
  gate[(size_t)b*Cn + threadIdx.x] = 1.f/(1.f+__expf(-acc));
}

// out (+)= msg * gate   (slice-sized; init on first pair)
__global__ __launch_bounds__(256) void accum_kernel(
    const float* __restrict__ msg, const float* __restrict__ gate,
    float* __restrict__ outs, int init)
{
  const size_t idx = (size_t)blockIdx.x*256 + threadIdx.x;
  if (idx >= SLICEsz) return;
  const size_t t_ = idx / Nn;
  const int c = (int)(t_ & 255);
  const int b = (int)(t_ >> 8);
  const float v = msg[idx] * gate[(size_t)b*Cn + c];
  outs[idx] = init ? v : (outs[idx] + v);
}

// hi = iia*hi + (1-iia)*outi   (in place, slice)
__global__ __launch_bounds__(256) void comb_kernel(float* __restrict__ hi,
    const float* __restrict__ outi, const float* __restrict__ iia)
{
  const size_t idx = (size_t)blockIdx.x*256 + threadIdx.x;
  if (idx >= SLICEsz) return;
  const float a = *iia;
  hi[idx] = a*hi[idx] + (1.f-a)*outi[idx];
}

// rh = sigmoid(zrq[:,256:512]) * h   (slice-local)
__global__ __launch_bounds__(256) void rh_kernel(const float* __restrict__ zrq,
    const float* __restrict__ h, float* __restrict__ rh)
{
  const size_t idx = (size_t)blockIdx.x*256 + threadIdx.x;
  if (idx >= SLICEsz) return;
  const int n_ = (int)(idx % Nn);
  const size_t t_ = idx / Nn;
  const int c = (int)(t_ & 255);
  const size_t s = t_ >> 8;
  float r = zrq[(s*512 + 256 + c)*Nn + n_];
  r = 1.f/(1.f+__expf(-r));
  rh[idx] = r*h[idx];
}

// nh = (1-z)*h + z*tanh(hq) + h,  z = sigmoid(zrq[:,0:256])  (slice-local)
__global__ __launch_bounds__(256) void nh_kernel(const float* __restrict__ zrq,
    const float* __restrict__ hq, const float* __restrict__ h,
    float* __restrict__ nh)
{
  const size_t idx = (size_t)blockIdx.x*256 + threadIdx.x;
  if (idx >= SLICEsz) return;
  const int n_ = (int)(idx % Nn);
  const size_t t_ = idx / Nn;
  const int c = (int)(t_ & 255);
  const size_t s = t_ >> 8;
  float z = zrq[(s*512 + c)*Nn + n_];
  z = 1.f/(1.f+__expf(-z));
  const float hv = h[idx];
  nh[idx] = (1.f-z)*hv + z*tanhf(hq[idx]) + hv;
}

// ---------------------------------------------------------------------------
// Host orchestration
// ---------------------------------------------------------------------------
static const int PJ[5][4] = {{1,2,0,0},{0,2,3,0},{0,1,3,4},{1,2,4,0},{2,3,0,0}};
static const int PNP[5]   = {2,3,4,3,2};

extern "C" void kernel_launch(void* const* d_in, const int* in_sizes, int n_in,
                              void* d_out, int out_size, void* d_ws, size_t ws_size,
                              hipStream_t stream)
{
  (void)in_sizes; (void)n_in; (void)out_size;
  const float* x   = (const float*)d_in[0];
  const float* ing = (const float*)d_in[1];
  const float* inb = (const float*)d_in[2];
  const float* iqw = (const float*)d_in[3];
  const float* iqb = (const float*)d_in[4];
  const float* ikw = (const float*)d_in[5];
  const float* ikb = (const float*)d_in[6];
  const float* ivw = (const float*)d_in[7];
  const float* ivb = (const float*)d_in[8];
  const float* iow = (const float*)d_in[9];
  const float* iob = (const float*)d_in[10];
  const float* iong= (const float*)d_in[11];
  const float* ionb= (const float*)d_in[12];
  const float* ia  = (const float*)d_in[13];
  const float* eng = (const float*)d_in[14];
  const float* enb = (const float*)d_in[15];
  const float* rpe = (const float*)d_in[16];
  const float* mw  = (const float*)d_in[17];
  const float* mb  = (const float*)d_in[18];
  const float* eqw = (const float*)d_in[19];
  const float* eqb = (const float*)d_in[20];
  const float* ekw = (const float*)d_in[21];
  const float* ekb = (const float*)d_in[22];
  const float* evw = (const float*)d_in[23];
  const float* evb = (const float*)d_in[24];
  const float* gw  = (const float*)d_in[25];
  const float* gb  = (const float*)d_in[26];
  const float* eow = (const float*)d_in[27];
  const float* eob = (const float*)d_in[28];
  const float* eong= (const float*)d_in[29];
  const float* eonb= (const float*)d_in[30];
  const float* iia = (const float*)d_in[31];
  const float* zrw = (const float*)d_in[32];
  const float* zrb = (const float*)d_in[33];
  const float* hww = (const float*)d_in[34];
  const float* hwb = (const float*)d_in[35];
  const float* ng  = (const float*)d_in[36];
  const float* nbg = (const float*)d_in[37];

  // Workspace layout (floats). Total = 43,719,680 floats = 166.8 MiB.
  float* W = (float*)d_ws;
  size_t off = 0;
  float* h      = W + off; off += FULLsz + 1024;   // persistent state
  float* p0     = W + off; off += SLA;             // k / y / msg / zrq-lo
  float* p1     = W + off; off += SLA;             // v / ke / msgc / zrq-hi
  float* p2     = W + off; off += SLA;             // o / ve / nh-src
  float* xsl    = W + off; off += SLA;             // xn slice / rh / nh
  float* qsl    = W + off; off += SLA;             // q slice / hq
  float* osl    = W + off; off += SLA;             // inter accumulation slice
  float* meanXb = W + off; off += Bn*Cn;
  float* meanM  = W + off; off += Bn*Cn;
  float* gateb  = W + off; off += Bn*Cn;
  float* zrq    = p0;                              // spans p0..p1 (GRU phase)
  if (ws_size < off * sizeof(float)) return;       // diagnostic guard

  float* hi = (float*)d_out;                       // full arena: intra out / comb

  hipMemcpyAsync(h, x, FULLsz*sizeof(float), hipMemcpyDeviceToDevice, stream);

  const int gridSlc = (int)((SLICEsz + 255) / 256);   // 15,488 exact

  for (int it = 0; it < NITERn; ++it){
    // ---------------- intra_all (per slice) ----------------
    for (int s = 0; s < Sn; ++s){
      const float* hs = h + (size_t)s*SLICEsz;
      ln_kernel<<<Bn,256,0,stream>>>(hs, ing, inb, xsl, nullptr, nullptr, 0);
      conv3x3_kernel<<<dim3(Bn,4),128,0,stream>>>(xsl, nullptr, 256, 256, 256, iqw, iqb, qsl);
      conv3x3_kernel<<<dim3(Bn,4),128,0,stream>>>(xsl, nullptr, 256, 256, 256, ikw, ikb, p0);
      conv3x3_kernel<<<dim3(Bn,4),128,0,stream>>>(xsl, nullptr, 256, 256, 256, ivw, ivb, p1);
      attn_kernel<256,4,4><<<Bn,256,0,stream>>>(qsl, p0, p1, p2);
      conv3x3_kernel<<<dim3(Bn,4),128,0,stream>>>(p2, nullptr, 256, 256, 256, iow, iob, p0);
      ln_kernel<<<Bn,256,0,stream>>>(p0, iong, ionb, hi + (size_t)s*SLICEsz, ia, xsl, 1);
    }

    // ---------------- inter (per i, per pair) ----------------
    for (int i = 0; i < Sn; ++i){
      ln_kernel<<<Bn,256,0,stream>>>(h + (size_t)i*SLICEsz, eng, enb, xsl, nullptr, nullptr, 0);
      conv3x3_kernel<<<dim3(Bn,4),128,0,stream>>>(xsl, nullptr, 256, 256, 256, eqw, eqb, qsl);
      mean_kernel<<<dim3(Bn,32),128,0,stream>>>(xsl, meanXb);
      const int np = PNP[i];
      for (int pl = 0; pl < np; ++pl){
        const int j = PJ[i][pl];
        const float tc0 = (i < j) ? 1.f : -1.f;
        const float tc1 = fabsf((float)(i - j)) * 0.5f;
        const int ri = (((i - j + 1) % 4) + 4) % 4;
        conv3x3_m_kernel<<<dim3(Bn,4),128,0,stream>>>(h + (size_t)j*SLICEsz,
            rpe + (size_t)ri*Nn, tc0, tc1, mw, mb, p0);                          // y
        conv3x3_kernel<<<dim3(Bn,4),128,0,stream>>>(p0, nullptr, 256, 256, 256, ekw, ekb, p1); // ke
        conv3x3_kernel<<<dim3(Bn,4),128,0,stream>>>(p0, nullptr, 256, 256, 256, evw, evb, p2); // ve
        attn_kernel<32,2,1><<<Bn*HEADSn,256,0,stream>>>(qsl, p1, p2, p0);        // msg_raw
        conv3x3_kernel<<<dim3(Bn,4),128,0,stream>>>(p0, nullptr, 256, 256, 256, eow, eob, p1);
        ln_kernel<<<Bn,256,0,stream>>>(p1, eong, eonb, p0, nullptr, nullptr, 1); // msg
        mean_kernel<<<dim3(Bn,32),128,0,stream>>>(p0, meanM);
        gate_kernel<<<Bn,256,0,stream>>>(meanXb, meanM, gw, gb, gateb);
        accum_kernel<<<gridSlc,256,0,stream>>>(p0, gateb, osl, pl == 0);
      }
      comb_kernel<<<gridSlc,256,0,stream>>>(hi + (size_t)i*SLICEsz, osl, iia);   // hi=comb
    }

    // ---------------- GRU + final LN (per slice) ----------------
    for (int s = 0; s < Sn; ++s){
      const float* hs = h + (size_t)s*SLICEsz;
      float* cs = hi + (size_t)s*SLICEsz;   // comb
      conv3x3_kernel<<<dim3(Bn,8),128,0,stream>>>(cs, hs, 256, 512, 512, zrw, zrb, zrq);
      rh_kernel<<<gridSlc,256,0,stream>>>(zrq, hs, xsl);                          // xsl = r*h
      conv3x3_kernel<<<dim3(Bn,4),128,0,stream>>>(cs, xsl, 256, 512, 256, hww, hwb, qsl); // hq
      nh_kernel<<<gridSlc,256,0,stream>>>(zrq, qsl, hs, xsl);                     // xsl = nh
      float* dst = (it == NITERn-1) ? cs : (h + (size_t)s*SLICEsz);
      ln_kernel<<<Bn,256,0,stream>>>(xsl, ng, nbg, dst, nullptr, nullptr, 0);
    }
  }
}

// Round 3
// 33643.375 us; speedup vs baseline: 11.0860x; 11.0860x over previous
//
#include <hip/hip_runtime.h>
#include <cstdint>
#include <cstddef>
#include <cmath>

// ---------------------------------------------------------------------------
// LiveSAL round 3: convs moved to bf16 MFMA implicit-GEMM (per-tap GEMM,
// fp32 accumulate). Everything else (LN, attention, gate, GRU elementwise)
// is the verified R2 fp32 code. Interchange format stays NCHW fp32.
// ---------------------------------------------------------------------------

#define Sn 5
#define Bn 128
#define Cn 256
#define Nn 121          // 11*11
#define HEADSn 8
#define NITERn 2
#define EPSf 1e-5f
#define SCALEf 0.0625f  // 256^-0.5
#define CHWn (Cn*Nn)    // 30976

static const size_t SLICEsz = (size_t)Bn*CHWn;       // 3,964,928 floats
static const size_t FULLsz  = (size_t)Sn*SLICEsz;    // 19,824,640 floats
static const size_t SLA     = SLICEsz + 1024;        // padded slice arena

typedef __attribute__((ext_vector_type(8))) short short8;
typedef __attribute__((ext_vector_type(4))) float f32x4;

static __device__ __forceinline__ short f2bf(float f){
  union { float f; unsigned u; } x; x.f = f;
  unsigned r = (x.u + 0x7FFFu + ((x.u >> 16) & 1u)) >> 16;   // RNE
  return (short)r;
}

// ---------------------------------------------------------------------------
// Weight prep: fp32 [Cout][Cin][3][3] -> bf16 [Cout][9][Cinp] (zero-padded K).
// grid = (Cout, 9), block = 128.
// ---------------------------------------------------------------------------
__global__ __launch_bounds__(128) void wprep_kernel(
    const float* __restrict__ w, short* __restrict__ o, int Cin, int Cinp)
{
  const int co = blockIdx.x, tap = blockIdx.y;
  short* orow = o + ((size_t)co*9 + tap)*Cinp;
  const float* wrow = w + (size_t)co*Cin*9 + tap;
  for (int ci = threadIdx.x; ci < Cinp; ci += 128)
    orow[ci] = (ci < Cin) ? f2bf(wrow[(size_t)ci*9]) : (short)0;
}

// ---------------------------------------------------------------------------
// MFMA conv3x3, pad=1, 11x11. One sample per block.x; block = 4 waves,
// block tile 128co x 64px, wave tile 64co x 32px. 16x16x32 bf16 MFMA.
// A (weights) loaded straight from global bf16 [co][tap][Cinp] (k-contig).
// B (activations) staged per 128-ci group into LDS [px][ci] bf16 (stride 136,
// rows 121..127 zeroed = tap-shift OOB sentinel).
// Input may be a channel-concat of inA (cinA ch) + inB; mMode adds the
// m-conv extra channels (256=tc0, 257=tc1, 258=rpe row).
// ---------------------------------------------------------------------------
__global__ __launch_bounds__(256) void conv_mfma_kernel(
    const float* __restrict__ inA, const float* __restrict__ inB,
    int cinA, int Cin, int Cinp, int Cout,
    const short* __restrict__ wbf, const float* __restrict__ bias,
    float* __restrict__ out,
    int mMode, float tc0, float tc1, const float* __restrict__ rp)
{
  __shared__ short Xs[128*136];
  const int samp = blockIdx.x;
  const int coB  = blockIdx.y * 128;
  const int pxB  = blockIdx.z * 64;
  const int t    = threadIdx.x;
  const int lane = t & 63;
  const int wv   = t >> 6;
  const int wy   = wv >> 1;      // co 64-half within block
  const int wx   = wv & 1;       // px 32-half within block
  const int l15  = lane & 15;
  const int quad = lane >> 4;

  int nout[2], py[2], pxx[2];
  #pragma unroll
  for (int ns = 0; ns < 2; ++ns){
    nout[ns] = pxB + wx*32 + ns*16 + l15;
    py[ns]  = nout[ns] / 11;
    pxx[ns] = nout[ns] % 11;
  }

  f32x4 acc[4][2];
  #pragma unroll
  for (int ms = 0; ms < 4; ++ms)
    #pragma unroll
    for (int ns = 0; ns < 2; ++ns) acc[ms][ns] = (f32x4){0.f,0.f,0.f,0.f};

  const float* baseA = inA + (size_t)samp*(size_t)cinA*Nn;
  const float* baseB = inB ? inB + (size_t)samp*(size_t)(Cin-cinA)*Nn : nullptr;

  const int ngrp = (Cin + 127) >> 7;
  for (int grp = 0; grp < ngrp; ++grp){
    __syncthreads();
    // ---- stage 128 ci x 128 px into LDS as bf16 [px][ci] ----
    for (int e = t; e < 128*128; e += 256){
      const int px = e & 127, cil = e >> 7;
      const int ci = grp*128 + cil;
      float v = 0.f;
      if (px < Nn && ci < Cin){
        if (mMode && ci >= 256)
          v = (ci == 256) ? tc0 : (ci == 257) ? tc1 : rp[px];
        else if (ci < cinA) v = baseA[(size_t)ci*Nn + px];
        else                v = baseB[(size_t)(ci-cinA)*Nn + px];
      }
      Xs[px*136 + cil] = f2bf(v);
    }
    __syncthreads();

    const int rem = Cin - grp*128;
    const int nkc = (rem >= 128) ? 4 : ((rem + 31) >> 5);

    for (int tap = 0; tap < 9; ++tap){
      const int dy = tap/3 - 1, dx = tap%3 - 1;
      int pp[2];
      #pragma unroll
      for (int ns = 0; ns < 2; ++ns){
        const int yy = py[ns] + dy, xx = pxx[ns] + dx;
        const bool ok = (nout[ns] < Nn) && yy >= 0 && yy < 11 && xx >= 0 && xx < 11;
        pp[ns] = ok ? yy*11 + xx : Nn;   // row 121 = zero sentinel
      }
      const short* wb0 = wbf + ((size_t)(coB + wy*64 + l15)*9 + tap)*Cinp
                             + grp*128 + quad*8;
      for (int kc = 0; kc < nkc; ++kc){
        short8 a[4], b[2];
        #pragma unroll
        for (int ms = 0; ms < 4; ++ms)
          a[ms] = *(const short8*)(wb0 + (size_t)ms*16*9*Cinp + kc*32);
        #pragma unroll
        for (int ns = 0; ns < 2; ++ns)
          b[ns] = *(const short8*)(&Xs[pp[ns]*136 + kc*32 + quad*8]);
        #pragma unroll
        for (int ms = 0; ms < 4; ++ms)
          #pragma unroll
          for (int ns = 0; ns < 2; ++ns)
            acc[ms][ns] = __builtin_amdgcn_mfma_f32_16x16x32_bf16(
                              a[ms], b[ns], acc[ms][ns], 0, 0, 0);
      }
    }
  }

  // ---- epilogue: C layout col=lane&15 (n), row=quad*4+r (m) ----
  #pragma unroll
  for (int ms = 0; ms < 4; ++ms)
    #pragma unroll
    for (int ns = 0; ns < 2; ++ns){
      const int n = nout[ns];
      if (n < Nn){
        const int mbase = coB + wy*64 + ms*16 + quad*4;
        #pragma unroll
        for (int r = 0; r < 4; ++r)
          out[((size_t)samp*Cout + mbase + r)*Nn + n] = acc[ms][ns][r] + bias[mbase + r];
      }
    }
}

// ---------------------------------------------------------------------------
// LayerNorm over (C,H,W) per sample. out = alpha*maybe_relu(LN(x)*g+b)+addend
// ---------------------------------------------------------------------------
__global__ __launch_bounds__(256) void ln_kernel(
    const float* __restrict__ x, const float* __restrict__ g, const float* __restrict__ bb,
    float* __restrict__ out, const float* __restrict__ alpha,
    const float* __restrict__ addend, int relu)
{
  const size_t base = (size_t)blockIdx.x * CHWn;
  const float* xs = x + base;
  float sum = 0.f, ss = 0.f;
  for (int i = threadIdx.x; i < CHWn; i += 256){
    float v = xs[i]; sum += v; ss += v*v;
  }
  #pragma unroll
  for (int o = 32; o > 0; o >>= 1){ sum += __shfl_down(sum, o, 64); ss += __shfl_down(ss, o, 64); }
  __shared__ float r1[4], r2[4];
  const int wid = threadIdx.x >> 6;
  if ((threadIdx.x & 63) == 0){ r1[wid] = sum; r2[wid] = ss; }
  __syncthreads();
  sum = r1[0]+r1[1]+r1[2]+r1[3];
  ss  = r2[0]+r2[1]+r2[2]+r2[3];
  const float mean = sum * (1.f/CHWn);
  const float var  = ss * (1.f/CHWn) - mean*mean;
  const float inv  = rsqrtf(var + EPSf);
  const float a = alpha ? *alpha : 1.f;
  float* os = out + base;
  const float* ad = addend ? addend + base : nullptr;
  for (int i = threadIdx.x; i < CHWn; i += 256){
    float v = (xs[i] - mean) * inv * g[i] + bb[i];
    if (relu) v = fmaxf(v, 0.f);
    v *= a;
    if (ad) v += ad[i];
    os[i] = v;
  }
}

// ---------------------------------------------------------------------------
// Fused attention per (sample, head) — verified R2 fp32 kernel.
// ---------------------------------------------------------------------------
template<int HDt, int CPT, int NPASS>
__global__ __launch_bounds__(256) void attn_kernel(
    const float* __restrict__ q, const float* __restrict__ k, const float* __restrict__ v,
    float* __restrict__ o)
{
  __shared__ float T[Nn*132];
  const int nh_ = Cn / HDt;
  const int samp = blockIdx.x / nh_;
  const int hh = blockIdx.x % nh_;
  const size_t koff = ((size_t)samp*Cn + hh*HDt)*Nn;
  const int t = threadIdx.x;
  {
    const int tn = t >> 4, tm = t & 15;
    const int n0 = tn*8, m0 = tm*8;
    float acc[8][8];
    #pragma unroll
    for (int a2=0;a2<8;a2++)
      #pragma unroll
      for (int b2=0;b2<8;b2++) acc[a2][b2] = 0.f;
    const float* qp = q + koff + n0;
    const float* kp = k + koff + m0;
    #pragma unroll 2
    for (int d=0; d<HDt; ++d){
      float qv[8], kv[8];
      #pragma unroll
      for (int j2=0;j2<8;j2++){ qv[j2] = qp[d*Nn + j2]; kv[j2] = kp[d*Nn + j2]; }
      #pragma unroll
      for (int a2=0;a2<8;a2++)
        #pragma unroll
        for (int b2=0;b2<8;b2++) acc[a2][b2] = fmaf(qv[a2], kv[b2], acc[a2][b2]);
    }
    #pragma unroll
    for (int b2=0;b2<8;b2++){
      const int m = m0 + b2;
      if (m < Nn){
        #pragma unroll
        for (int a2=0;a2<8;a2++) T[m*132 + n0 + a2] = acc[a2][b2] * SCALEf;
      }
    }
  }
  __syncthreads();
  if (t < Nn){
    float mx = -1e30f;
    for (int m2=0;m2<Nn;m2++) mx = fmaxf(mx, T[m2*132+t]);
    float sum = 0.f;
    for (int m2=0;m2<Nn;m2++){ float e = __expf(T[m2*132+t]-mx); sum += e; T[m2*132+t] = e; }
    const float invs = 1.f/sum;
    for (int m2=0;m2<Nn;m2++) T[m2*132+t] *= invs;
  }
  __syncthreads();
  {
    const int ng_ = t & 15, cg = t >> 4;
    const int an0 = ng_*8;
    for (int pass=0; pass<NPASS; ++pass){
      const int c0 = pass*64 + cg*CPT;
      float av[CPT][8];
      #pragma unroll
      for (int ci2=0;ci2<CPT;ci2++)
        #pragma unroll
        for (int j2=0;j2<8;j2++) av[ci2][j2] = 0.f;
      for (int m2=0;m2<Nn;m2++){
        float tv[8];
        #pragma unroll
        for (int j2=0;j2<8;j2++) tv[j2] = T[m2*132 + an0 + j2];
        #pragma unroll
        for (int ci2=0;ci2<CPT;ci2++){
          const float vv = v[koff + (size_t)(c0+ci2)*Nn + m2];
          #pragma unroll
          for (int j2=0;j2<8;j2++) av[ci2][j2] = fmaf(vv, tv[j2], av[ci2][j2]);
        }
      }
      #pragma unroll
      for (int ci2=0;ci2<CPT;ci2++){
        float* op = o + koff + (size_t)(c0+ci2)*Nn + an0;
        #pragma unroll
        for (int j2=0;j2<8;j2++) if (an0+j2 < Nn) op[j2] = av[ci2][j2];
      }
    }
  }
}

// Spatial mean per (local sample, channel). grid=(Bn,32).
__global__ __launch_bounds__(128) void mean_kernel(const float* __restrict__ x, float* __restrict__ out)
{
  const int s = blockIdx.x; const int c0 = blockIdx.y*8;
  __shared__ float r[2];
  for (int cc=0; cc<8; ++cc){
    const int c = c0+cc;
    float v = 0.f;
    if (threadIdx.x < Nn) v = x[((size_t)s*Cn + c)*Nn + threadIdx.x];
    #pragma unroll
    for (int o=32;o>0;o>>=1) v += __shfl_down(v, o, 64);
    if ((threadIdx.x & 63) == 0) r[threadIdx.x>>6] = v;
    __syncthreads();
    if (threadIdx.x == 0) out[(size_t)s*Cn + c] = (r[0]+r[1]) * (1.f/Nn);
    __syncthreads();
  }
}

// gate[b,c] = sigmoid( gw[c,:] . [meanX(b); meanM(b)] + gb[c] )
__global__ __launch_bounds__(256) void gate_kernel(
    const float* __restrict__ meanX, const float* __restrict__ meanM,
    const float* __restrict__ gw, const float* __restrict__ gb,
    float* __restrict__ gate)
{
  const int b = blockIdx.x;
  __shared__ float mv[512];
  mv[threadIdx.x]     = meanX[(size_t)b*Cn + threadIdx.x];
  mv[256+threadIdx.x] = meanM[(size_t)b*Cn + threadIdx.x];
  __syncthreads();
  const float* gr = gw + (size_t)threadIdx.x*512;
  float acc = gb[threadIdx.x];
  for (int k2=0;k2<512;k2++) acc = fmaf(gr[k2], mv[k2], acc);
  gate[(size_t)b*Cn + threadIdx.x] = 1.f/(1.f+__expf(-acc));
}

// out (+)= msg * gate
__global__ __launch_bounds__(256) void accum_kernel(
    const float* __restrict__ msg, const float* __restrict__ gate,
    float* __restrict__ outs, int init)
{
  const size_t idx = (size_t)blockIdx.x*256 + threadIdx.x;
  if (idx >= SLICEsz) return;
  const size_t t_ = idx / Nn;
  const int c = (int)(t_ & 255);
  const int b = (int)(t_ >> 8);
  const float v = msg[idx] * gate[(size_t)b*Cn + c];
  outs[idx] = init ? v : (outs[idx] + v);
}

// hi = iia*hi + (1-iia)*outi
__global__ __launch_bounds__(256) void comb_kernel(float* __restrict__ hi,
    const float* __restrict__ outi, const float* __restrict__ iia)
{
  const size_t idx = (size_t)blockIdx.x*256 + threadIdx.x;
  if (idx >= SLICEsz) return;
  const float a = *iia;
  hi[idx] = a*hi[idx] + (1.f-a)*outi[idx];
}

// rh = sigmoid(zrq[:,256:512]) * h
__global__ __launch_bounds__(256) void rh_kernel(const float* __restrict__ zrq,
    const float* __restrict__ h, float* __restrict__ rh)
{
  const size_t idx = (size_t)blockIdx.x*256 + threadIdx.x;
  if (idx >= SLICEsz) return;
  const int n_ = (int)(idx % Nn);
  const size_t t_ = idx / Nn;
  const int c = (int)(t_ & 255);
  const size_t s = t_ >> 8;
  float r = zrq[(s*512 + 256 + c)*Nn + n_];
  r = 1.f/(1.f+__expf(-r));
  rh[idx] = r*h[idx];
}

// nh = (1-z)*h + z*tanh(hq) + h
__global__ __launch_bounds__(256) void nh_kernel(const float* __restrict__ zrq,
    const float* __restrict__ hq, const float* __restrict__ h,
    float* __restrict__ nh)
{
  const size_t idx = (size_t)blockIdx.x*256 + threadIdx.x;
  if (idx >= SLICEsz) return;
  const int n_ = (int)(idx % Nn);
  const size_t t_ = idx / Nn;
  const int c = (int)(t_ & 255);
  const size_t s = t_ >> 8;
  float z = zrq[(s*512 + c)*Nn + n_];
  z = 1.f/(1.f+__expf(-z));
  const float hv = h[idx];
  nh[idx] = (1.f-z)*hv + z*tanhf(hq[idx]) + hv;
}

// ---------------------------------------------------------------------------
// Host orchestration
// ---------------------------------------------------------------------------
static const int PJ[5][4] = {{1,2,0,0},{0,2,3,0},{0,1,3,4},{1,2,4,0},{2,3,0,0}};
static const int PNP[5]   = {2,3,4,3,2};

extern "C" void kernel_launch(void* const* d_in, const int* in_sizes, int n_in,
                              void* d_out, int out_size, void* d_ws, size_t ws_size,
                              hipStream_t stream)
{
  (void)in_sizes; (void)n_in; (void)out_size;
  const float* x   = (const float*)d_in[0];
  const float* ing = (const float*)d_in[1];
  const float* inb = (const float*)d_in[2];
  const float* iqw = (const float*)d_in[3];
  const float* iqb = (const float*)d_in[4];
  const float* ikw = (const float*)d_in[5];
  const float* ikb = (const float*)d_in[6];
  const float* ivw = (const float*)d_in[7];
  const float* ivb = (const float*)d_in[8];
  const float* iow = (const float*)d_in[9];
  const float* iob = (const float*)d_in[10];
  const float* iong= (const float*)d_in[11];
  const float* ionb= (const float*)d_in[12];
  const float* ia  = (const float*)d_in[13];
  const float* eng = (const float*)d_in[14];
  const float* enb = (const float*)d_in[15];
  const float* rpe = (const float*)d_in[16];
  const float* mw  = (const float*)d_in[17];
  const float* mb  = (const float*)d_in[18];
  const float* eqw = (const float*)d_in[19];
  const float* eqb = (const float*)d_in[20];
  const float* ekw = (const float*)d_in[21];
  const float* ekb = (const float*)d_in[22];
  const float* evw = (const float*)d_in[23];
  const float* evb = (const float*)d_in[24];
  const float* gw  = (const float*)d_in[25];
  const float* gb  = (const float*)d_in[26];
  const float* eow = (const float*)d_in[27];
  const float* eob = (const float*)d_in[28];
  const float* eong= (const float*)d_in[29];
  const float* eonb= (const float*)d_in[30];
  const float* iia = (const float*)d_in[31];
  const float* zrw = (const float*)d_in[32];
  const float* zrb = (const float*)d_in[33];
  const float* hww = (const float*)d_in[34];
  const float* hwb = (const float*)d_in[35];
  const float* ng  = (const float*)d_in[36];
  const float* nbg = (const float*)d_in[37];

  // ---- workspace layout (floats) ----
  float* W = (float*)d_ws;
  size_t off = 0;
  float* h      = W + off; off += FULLsz + 1024;   // persistent state (fp32)
  float* p0     = W + off; off += SLA;             // k / y / msg / zrq-lo
  float* p1     = W + off; off += SLA;             // v / ke / msgc / zrq-hi
  float* p2     = W + off; off += SLA;             // o / ve
  float* xsl    = W + off; off += SLA;             // xn / rh / nh
  float* qsl    = W + off; off += SLA;             // q / hq
  float* osl    = W + off; off += SLA;             // inter accumulation
  float* meanXb = W + off; off += Bn*Cn;
  float* meanM  = W + off; off += Bn*Cn;
  float* gateb  = W + off; off += Bn*Cn;
  // bf16 weight buffers (shorts), allocated on float boundary
  short* WB = (short*)(W + off);
  size_t so = 0;
  short* iqB = WB + so; so += (size_t)256*9*256;
  short* ikB = WB + so; so += (size_t)256*9*256;
  short* ivB = WB + so; so += (size_t)256*9*256;
  short* ioB = WB + so; so += (size_t)256*9*256;
  short* eqB = WB + so; so += (size_t)256*9*256;
  short* ekB = WB + so; so += (size_t)256*9*256;
  short* evB = WB + so; so += (size_t)256*9*256;
  short* eoB = WB + so; so += (size_t)256*9*256;
  short* mB_ = WB + so; so += (size_t)256*9*384;
  short* zrB = WB + so; so += (size_t)512*9*512;
  short* hwB = WB + so; so += (size_t)256*9*512;
  off += (so + 1) / 2;
  float* zrq = p0;                                 // spans p0..p1 (GRU phase)
  if (ws_size < off * sizeof(float)) return;       // diagnostic guard

  float* hi = (float*)d_out;                       // full arena: intra out / comb

  hipMemcpyAsync(h, x, FULLsz*sizeof(float), hipMemcpyDeviceToDevice, stream);

  // ---- weight prep (once per call; ~18 MB of bf16) ----
  wprep_kernel<<<dim3(256,9),128,0,stream>>>(iqw, iqB, 256, 256);
  wprep_kernel<<<dim3(256,9),128,0,stream>>>(ikw, ikB, 256, 256);
  wprep_kernel<<<dim3(256,9),128,0,stream>>>(ivw, ivB, 256, 256);
  wprep_kernel<<<dim3(256,9),128,0,stream>>>(iow, ioB, 256, 256);
  wprep_kernel<<<dim3(256,9),128,0,stream>>>(eqw, eqB, 256, 256);
  wprep_kernel<<<dim3(256,9),128,0,stream>>>(ekw, ekB, 256, 256);
  wprep_kernel<<<dim3(256,9),128,0,stream>>>(evw, evB, 256, 256);
  wprep_kernel<<<dim3(256,9),128,0,stream>>>(eow, eoB, 256, 256);
  wprep_kernel<<<dim3(256,9),128,0,stream>>>(mw,  mB_, 259, 384);
  wprep_kernel<<<dim3(512,9),128,0,stream>>>(zrw, zrB, 512, 512);
  wprep_kernel<<<dim3(256,9),128,0,stream>>>(hww, hwB, 512, 512);

  const int gridSlc = (int)(SLICEsz / 256);   // 15,488 exact

  // conv helper: regular conv (no m-extras)
  #define CONV(inA_, inB_, cinA_, Cin_, Cinp_, Cout_, wb_, bi_, out_)            \
    conv_mfma_kernel<<<dim3(Bn, (Cout_)/128, 2), 256, 0, stream>>>(              \
        inA_, inB_, cinA_, Cin_, Cinp_, Cout_, wb_, bi_, out_, 0, 0.f, 0.f, nullptr)

  for (int it = 0; it < NITERn; ++it){
    // ---------------- intra_all (per slice) ----------------
    for (int s = 0; s < Sn; ++s){
      const float* hs = h + (size_t)s*SLICEsz;
      ln_kernel<<<Bn,256,0,stream>>>(hs, ing, inb, xsl, nullptr, nullptr, 0);
      CONV(xsl, nullptr, 256, 256, 256, 256, iqB, iqb, qsl);
      CONV(xsl, nullptr, 256, 256, 256, 256, ikB, ikb, p0);
      CONV(xsl, nullptr, 256, 256, 256, 256, ivB, ivb, p1);
      attn_kernel<256,4,4><<<Bn,256,0,stream>>>(qsl, p0, p1, p2);
      CONV(p2, nullptr, 256, 256, 256, 256, ioB, iob, p0);
      ln_kernel<<<Bn,256,0,stream>>>(p0, iong, ionb, hi + (size_t)s*SLICEsz, ia, xsl, 1);
    }

    // ---------------- inter (per i, per pair) ----------------
    for (int i = 0; i < Sn; ++i){
      ln_kernel<<<Bn,256,0,stream>>>(h + (size_t)i*SLICEsz, eng, enb, xsl, nullptr, nullptr, 0);
      CONV(xsl, nullptr, 256, 256, 256, 256, eqB, eqb, qsl);
      mean_kernel<<<dim3(Bn,32),128,0,stream>>>(xsl, meanXb);
      const int np = PNP[i];
      for (int pl = 0; pl < np; ++pl){
        const int j = PJ[i][pl];
        const float tc0 = (i < j) ? 1.f : -1.f;
        const float tc1 = fabsf((float)(i - j)) * 0.5f;
        const int ri = (((i - j + 1) % 4) + 4) % 4;
        conv_mfma_kernel<<<dim3(Bn,2,2),256,0,stream>>>(
            h + (size_t)j*SLICEsz, nullptr, 256, 259, 384, 256, mB_, mb, p0,
            1, tc0, tc1, rpe + (size_t)ri*Nn);                                   // y
        CONV(p0, nullptr, 256, 256, 256, 256, ekB, ekb, p1);                     // ke
        CONV(p0, nullptr, 256, 256, 256, 256, evB, evb, p2);                     // ve
        attn_kernel<32,2,1><<<Bn*HEADSn,256,0,stream>>>(qsl, p1, p2, p0);        // msg_raw
        CONV(p0, nullptr, 256, 256, 256, 256, eoB, eob, p1);
        ln_kernel<<<Bn,256,0,stream>>>(p1, eong, eonb, p0, nullptr, nullptr, 1); // msg
        mean_kernel<<<dim3(Bn,32),128,0,stream>>>(p0, meanM);
        gate_kernel<<<Bn,256,0,stream>>>(meanXb, meanM, gw, gb, gateb);
        accum_kernel<<<gridSlc,256,0,stream>>>(p0, gateb, osl, pl == 0);
      }
      comb_kernel<<<gridSlc,256,0,stream>>>(hi + (size_t)i*SLICEsz, osl, iia);   // hi=comb
    }

    // ---------------- GRU + final LN (per slice) ----------------
    for (int s = 0; s < Sn; ++s){
      const float* hs = h + (size_t)s*SLICEsz;
      float* cs = hi + (size_t)s*SLICEsz;   // comb
      CONV(cs, hs, 256, 512, 512, 512, zrB, zrb, zrq);
      rh_kernel<<<gridSlc,256,0,stream>>>(zrq, hs, xsl);                          // xsl = r*h
      CONV(cs, xsl, 256, 512, 512, 256, hwB, hwb, qsl);                           // hq
      nh_kernel<<<gridSlc,256,0,stream>>>(zrq, qsl, hs, xsl);                     // xsl = nh
      float* dst = (it == NITERn-1) ? cs : (h + (size_t)s*SLICEsz);
      ln_kernel<<<Bn,256,0,stream>>>(xsl, ng, nbg, dst, nullptr, nullptr, 0);
    }
  }
  #undef CONV
}